// Round 10
// baseline (1376.373 us; speedup 1.0000x reference)
//
#include <hip/hip_runtime.h>
#include <hip/hip_bf16.h>

#define F2   128           // float2/bf162 columns per row (256 features)
#define CAP  256           // padded CSR row capacity (max degree ~70 << CAP)
#define T_STEPS 8
#define LR_X 0.1f
#define EXT_BIT (1 << 24)
#define NBLK 512           // 2 blocks/CU x 256 CU -- cannot be rejected at VGPR<=256
#define NTHR (NBLK * 256)  // 131072 threads
#define NWV  (NBLK * 4)    // 2048 waves

typedef __hip_bfloat162 bf2;

__device__ __forceinline__ float ftanh(float x) {
    float ax = fabsf(x);
    float z  = __expf(-2.f * ax);
    float t  = (1.f - z) * __builtin_amdgcn_rcpf(1.f + z);
    return copysignf(t, x);
}
__device__ __forceinline__ float2 bf22f(const bf2 v) {
    return make_float2(__bfloat162float(v.x), __bfloat162float(v.y));
}
__device__ __forceinline__ bf2 f22bf(float x, float y) {
    bf2 r; r.x = __float2bfloat16(x); r.y = __float2bfloat16(y); return r;
}

// Device-scope sense-reversing barrier; relaxed polls (no per-poll cache inv),
// one release fence at arrival, one acquire fence at departure.
__device__ __forceinline__ void gbar(int* bar, int gen) {
    __syncthreads();
    if (threadIdx.x == 0) {
        __threadfence();
        int old = __hip_atomic_fetch_add(&bar[0], 1, __ATOMIC_RELAXED,
                                         __HIP_MEMORY_SCOPE_AGENT);
        if (old == NBLK - 1) {
            __hip_atomic_store(&bar[0], 0, __ATOMIC_RELAXED, __HIP_MEMORY_SCOPE_AGENT);
            __hip_atomic_store(&bar[1], gen, __ATOMIC_RELEASE, __HIP_MEMORY_SCOPE_AGENT);
        } else {
            while (__hip_atomic_load(&bar[1], __ATOMIC_RELAXED,
                                     __HIP_MEMORY_SCOPE_AGENT) < gen)
                __builtin_amdgcn_s_sleep(2);
        }
        __threadfence();
    }
    __syncthreads();
}

// Gather-accumulate over CSR slots [s,e): even-j edges into A*, odd into B*.
// A0/B0 accumulate feature column f0, A1/B1 column f1 (order matches r7).
__device__ __forceinline__ void gacc(const int2* __restrict__ cw,
                                     const bf2* __restrict__ t2,
                                     int s, int e, int lane, int f0, int f1,
                                     float2& A0, float2& A1, float2& B0, float2& B1) {
    for (int base = s; base < e; base += 64) {
        const int n = min(64, e - base);
        int c = 0; float ww = 0.f;
        if (lane < n) { int2 p = cw[base + lane]; c = p.x; ww = __int_as_float(p.y); }
        int j = 0;
        for (; j + 2 <= n; j += 2) {
            const int   c0 = __shfl(c, j),  c1 = __shfl(c, j + 1);
            const float w0 = __shfl(ww, j), w1 = __shfl(ww, j + 1);
            const float2 t00 = bf22f(t2[c0 + f0]);
            const float2 t01 = bf22f(t2[c0 + f1]);
            const float2 t10 = bf22f(t2[c1 + f0]);
            const float2 t11 = bf22f(t2[c1 + f1]);
            A0.x = fmaf(w0, t00.x, A0.x); A0.y = fmaf(w0, t00.y, A0.y);
            A1.x = fmaf(w0, t01.x, A1.x); A1.y = fmaf(w0, t01.y, A1.y);
            B0.x = fmaf(w1, t10.x, B0.x); B0.y = fmaf(w1, t10.y, B0.y);
            B1.x = fmaf(w1, t11.x, B1.x); B1.y = fmaf(w1, t11.y, B1.y);
        }
        if (j < n) {
            const int c0 = __shfl(c, j); const float w0 = __shfl(ww, j);
            const float2 t00 = bf22f(t2[c0 + f0]);
            const float2 t01 = bf22f(t2[c0 + f1]);
            A0.x = fmaf(w0, t00.x, A0.x); A0.y = fmaf(w0, t00.y, A0.y);
            A1.x = fmaf(w0, t01.x, A1.x); A1.y = fmaf(w0, t01.y, A1.y);
        }
    }
}

// One persistent cooperative kernel: build + init + all 8 steps, state in
// global (L2-resident). Phases separated by gbar; grid-stride loops.
__global__ __launch_bounds__(256, 2) void k_all(
    const int* __restrict__ src, const int* __restrict__ dst,
    const float* __restrict__ w, const float* __restrict__ vin,
    float2* __restrict__ vals2 /* = d_out */, int* __restrict__ cnt,
    int* __restrict__ keyT, int* __restrict__ colS, int2* __restrict__ cw,
    bf2* __restrict__ th2, bf2* __restrict__ dd2,
    float2* __restrict__ predc2, float2* __restrict__ err2,
    int* __restrict__ nintA, int* __restrict__ bar,
    int N, int E, int NI)
{
    const int tid  = (int)threadIdx.x;
    const int lane = tid & 63;
    const int wv   = (int)blockIdx.x * 4 + (tid >> 6);
    const int gtid = (int)blockIdx.x * 256 + tid;
    const int f0 = lane, f1 = lane + 64;
    const float2* in2 = (const float2*)vin;
    int gen = 0;

    // ---- P0: zero degree counters; vals2 = values; th2 = tanh --------------
    for (int i = gtid; i < N; i += NTHR) cnt[i] = 0;
    for (int i = gtid; i < N * F2; i += NTHR) {
        const float2 v = in2[i];
        vals2[i] = v;
        th2[i] = f22bf(ftanh(v.x), ftanh(v.y));
    }
    gbar(bar, ++gen);

    // ---- P1: fill padded CSR slots (order fixed by rank in P2) -------------
    for (int e = gtid; e < E; e += NTHR) {
        const int sc = src[e], d = dst[e];
        const int p = atomicAdd(&cnt[d], 1);
        if (p < CAP) {
            keyT[d * CAP + p] = ((sc >= NI) ? EXT_BIT : 0) | e;
            colS[d * CAP + p] = sc;
        }
    }
    gbar(bar, ++gen);

    // ---- P2: deterministic rank-order + w[src,dst] gather, one wave/row ----
    for (int r = wv; r < N; r += NWV) {
        const int rbase = r * CAP;
        const int deg = min(cnt[r], CAP);
        int nint = 0;
        for (int i = lane; i < deg; i += 64) {
            const int myk = keyT[rbase + i];
            int rank = 0;
            for (int j = 0; j < deg; ++j)
                rank += (keyT[rbase + j] < myk) ? 1 : 0;
            const int sc = colS[rbase + i];
            int2 p; p.x = sc * F2; p.y = __float_as_int(w[(size_t)sc * N + r]);
            cw[rbase + rank] = p;
            nint += (myk < EXT_BIT) ? 1 : 0;
        }
        for (int o = 1; o < 64; o <<= 1) nint += __shfl_xor(nint, o);
        if (lane == 0) nintA[r] = nint;
    }
    gbar(bar, ++gen);

    // ---- 8 iterative steps -------------------------------------------------
    for (int t = 0; t < T_STEPS; ++t) {
        // pred: all rows
        for (int r = wv; r < N; r += NWV) {
            const int rbase = r * CAP, rowf = r * F2;
            const int ni = nintA[r];
            const int de = min(cnt[r], CAP);
            float2 A0 = {0,0}, A1 = {0,0}, B0 = {0,0}, B1 = {0,0};
            gacc(cw, th2, rbase, rbase + ni, lane, f0, f1, A0, A1, B0, B1);
            float2 pcA, pcB;
            if (t == 0) {
                float2 P0 = {0,0}, P1 = {0,0}, Q0 = {0,0}, Q1 = {0,0};
                gacc(cw, th2, rbase + ni, rbase + de, lane, f0, f1, P0, P1, Q0, Q1);
                pcA = make_float2(P0.x + Q0.x, P0.y + Q0.y);
                pcB = make_float2(P1.x + Q1.x, P1.y + Q1.y);
                predc2[rowf + f0] = pcA;
                predc2[rowf + f1] = pcB;
            } else {
                pcA = predc2[rowf + f0];
                pcB = predc2[rowf + f1];
            }
            const float2 vA = vals2[rowf + f0];
            const float2 vB = vals2[rowf + f1];
            float2 erA, erB;
            erA.x = vA.x - (pcA.x + A0.x + B0.x);
            erA.y = vA.y - (pcA.y + A0.y + B0.y);
            erB.x = vB.x - (pcB.x + A1.x + B1.x);
            erB.y = vB.y - (pcB.y + A1.y + B1.y);
            if (r < NI) { err2[rowf + f0] = erA; err2[rowf + f1] = erB; }
            const float uax = ftanh(erA.x), uay = ftanh(erA.y);
            const float ubx = ftanh(erB.x), uby = ftanh(erB.y);
            dd2[rowf + f0] = f22bf(1.f - uax * uax, 1.f - uay * uay);
            dd2[rowf + f1] = f22bf(1.f - ubx * ubx, 1.f - uby * uby);
        }
        gbar(bar, ++gen);

        // grad + update: internal rows
        for (int r = wv; r < NI; r += NWV) {
            const int rbase = r * CAP, rowf = r * F2;
            const int de = min(cnt[r], CAP);
            float2 G0 = {0,0}, G1 = {0,0}, H0 = {0,0}, H1 = {0,0};
            gacc(cw, dd2, rbase, rbase + de, lane, f0, f1, G0, G1, H0, H1);
            const float2 eA = err2[rowf + f0];
            const float2 eB = err2[rowf + f1];
            float2 vA = vals2[rowf + f0];
            float2 vB = vals2[rowf + f1];
            vA.x -= LR_X * (eA.x - (G0.x + H0.x));
            vA.y -= LR_X * (eA.y - (G0.y + H0.y));
            vB.x -= LR_X * (eB.x - (G1.x + H1.x));
            vB.y -= LR_X * (eB.y - (G1.y + H1.y));
            vals2[rowf + f0] = vA;
            vals2[rowf + f1] = vB;
            th2[rowf + f0] = f22bf(ftanh(vA.x), ftanh(vA.y));
            th2[rowf + f1] = f22bf(ftanh(vB.x), ftanh(vB.y));
        }
        gbar(bar, ++gen);
    }
}

// ---- Launch ---------------------------------------------------------------

extern "C" void kernel_launch(void* const* d_in, const int* in_sizes, int n_in,
                              void* d_out, int out_size, void* d_ws, size_t ws_size,
                              hipStream_t stream) {
    const float* values = (const float*)d_in[0];
    const float* w      = (const float*)d_in[1];
    const int*   edge   = (const int*)d_in[2];
    const int NF = in_sizes[0];            // N*F
    int N  = NF / 256;                     // 5000
    int E  = in_sizes[2] / 2;              // 160000
    int NI = in_sizes[3];                  // 2500
    const int NF2 = NF / 2;
    const int* srcp = edge;
    const int* dstp = edge + E;

    char* ws = (char*)d_ws;
    size_t off = 0;
    auto alloc = [&](size_t bytes) {
        void* p = ws + off;
        off = (off + bytes + 255) & ~(size_t)255;
        return p;
    };
    int*    cnt   = (int*)   alloc((size_t)N * sizeof(int));
    int*    nintA = (int*)   alloc((size_t)N * sizeof(int));
    int*    keyT  = (int*)   alloc((size_t)N * CAP * sizeof(int));
    int*    colS  = (int*)   alloc((size_t)N * CAP * sizeof(int));
    int2*   cw    = (int2*)  alloc((size_t)N * CAP * sizeof(int2));
    bf2*    th2   = (bf2*)   alloc((size_t)NF2 * sizeof(bf2));
    bf2*    dd2   = (bf2*)   alloc((size_t)NF2 * sizeof(bf2));
    float2* predc2= (float2*)alloc((size_t)NF2 * sizeof(float2));
    float2* err2  = (float2*)alloc((size_t)NF2 * sizeof(float2));
    int*    bar   = (int*)   alloc(2 * sizeof(int));
    (void)ws_size; (void)n_in; (void)out_size;

    float2* vals2 = (float2*)d_out;

    hipMemsetAsync(bar, 0, 2 * sizeof(int), stream);  // reset barrier each replay

    void* args[] = {(void*)&srcp, (void*)&dstp, (void*)&w, (void*)&values,
                    (void*)&vals2, (void*)&cnt, (void*)&keyT, (void*)&colS,
                    (void*)&cw, (void*)&th2, (void*)&dd2, (void*)&predc2,
                    (void*)&err2, (void*)&nintA, (void*)&bar,
                    (void*)&N, (void*)&E, (void*)&NI};
    hipLaunchCooperativeKernel((const void*)k_all, dim3(NBLK), dim3(256),
                               args, 0, stream);
}

// Round 11
// 214.847 us; speedup vs baseline: 6.4063x; 6.4063x over previous
//
#include <hip/hip_runtime.h>
#include <hip/hip_bf16.h>

#define FDIM 256
#define F2   128           // bf162 / float2 elements per row
#define CAP  256           // padded CSR row capacity (max degree ~70 << CAP)
#define T_STEPS 8
#define LR_X 0.1f
#define EXT_BIT (1 << 24)

typedef __hip_bfloat162 bf2;

__device__ __forceinline__ float ftanh(float x) {
    float ax = fabsf(x);
    float z  = __expf(-2.f * ax);
    float t  = (1.f - z) * __builtin_amdgcn_rcpf(1.f + z);
    return copysignf(t, x);
}
__device__ __forceinline__ float2 bf22f(const bf2 v) {
    return make_float2(__bfloat162float(v.x), __bfloat162float(v.y));
}
__device__ __forceinline__ bf2 f22bf(float x, float y) {
    bf2 r; r.x = __float2bfloat16(x); r.y = __float2bfloat16(y); return r;
}

// ---- Build (padded CSR: no scan) ------------------------------------------

// Fused: blocks [0,gE) scatter edges into padded rows; blocks [gE,..) init
// vals(d_out)/th2.
__global__ void k_fill_init(const int* __restrict__ src, const int* __restrict__ dst,
                            int* __restrict__ cnt, int* __restrict__ keyT,
                            int* __restrict__ colS, int E, int NI,
                            const float* __restrict__ vin, float* __restrict__ vals,
                            bf2* __restrict__ th2, int NF2, int gE) {
    const int b = (int)blockIdx.x;
    if (b < gE) {
        int e = b * 256 + (int)threadIdx.x;
        if (e < E) {
            int sc = src[e];
            int d  = dst[e];
            int p  = atomicAdd(&cnt[d], 1);       // cnt ends as degree
            if (p < CAP) {
                keyT[d * CAP + p] = ((sc >= NI) ? EXT_BIT : 0) | e;
                colS[d * CAP + p] = sc;
            }
        }
    } else {
        int i = (b - gE) * 256 + (int)threadIdx.x;
        if (i < NF2) {
            float2 v = ((const float2*)vin)[i];
            ((float2*)vals)[i] = v;
            th2[i] = f22bf(ftanh(v.x), ftanh(v.y));
        }
    }
}

// One WAVE per row: deterministic order via rank of key = (is_ext<<24)|eid.
// Writes fused (col*F2, w-bits) pairs, internal cols first; nint = #internal.
__global__ __launch_bounds__(256) void k_rank_scatter(
    const int* __restrict__ keyT, const int* __restrict__ colS,
    const int* __restrict__ cnt, const float* __restrict__ w,
    int2* __restrict__ cw, int* __restrict__ nintA, int nRows, int N) {
    const int wid  = (int)((blockIdx.x * blockDim.x + threadIdx.x) >> 6);
    const int lane = (int)(threadIdx.x & 63);
    if (wid >= nRows) return;
    const int base = wid * CAP;
    const int deg  = min(cnt[wid], CAP);
    int nInt = 0;
    for (int i = lane; i < deg; i += 64) {
        const int myk = keyT[base + i];
        int rank = 0;
        for (int j = 0; j < deg; ++j)
            rank += (keyT[base + j] < myk) ? 1 : 0;
        const int sc = colS[base + i];
        int2 p;
        p.x = sc * F2;
        p.y = __float_as_int(w[(size_t)sc * N + wid]);
        cw[base + rank] = p;
        nInt += (myk < EXT_BIT) ? 1 : 0;
    }
    for (int off = 1; off < 64; off <<= 1)
        nInt += __shfl_xor(nInt, off);
    if (lane == 0) nintA[wid] = nInt;
}

// ---- Loop kernels: 2 rows/block, 128 thr/row, shfl broadcast ----------------
// Chunk-0 (col,w) pairs are loaded SPECULATIVELY from the padded row before the
// degree arrives (always in-bounds; lanes >= deg never consumed) — cuts the
// per-block dependent-latency chain from 3 global loads to 2.

__device__ __forceinline__ void gchunk(int c, float ww, int n,
                                       const bf2* __restrict__ t2, int f,
                                       float& ax, float& ay, float& bx, float& by) {
    int j = 0;
    for (; j + 2 <= n; j += 2) {
        const int   c0 = __shfl(c, j),  c1 = __shfl(c, j + 1);
        const float w0 = __shfl(ww, j), w1 = __shfl(ww, j + 1);
        const float2 t0 = bf22f(t2[c0 + f]);
        const float2 t1 = bf22f(t2[c1 + f]);
        ax = fmaf(w0, t0.x, ax); ay = fmaf(w0, t0.y, ay);
        bx = fmaf(w1, t1.x, bx); by = fmaf(w1, t1.y, by);
    }
    if (j < n) {
        const int c0 = __shfl(c, j); const float w0 = __shfl(ww, j);
        const float2 t0 = bf22f(t2[c0 + f]);
        ax = fmaf(w0, t0.x, ax); ay = fmaf(w0, t0.y, ay);
    }
}

// Tail chunks (rare: deg > 64), guarded loads.
__device__ __forceinline__ void gtail(const int2* __restrict__ cw, int rbase,
                                      int s, int e, int lane,
                                      const bf2* __restrict__ t2, int f,
                                      float& ax, float& ay, float& bx, float& by) {
    for (int base = s; base < e; base += 64) {
        const int n = min(64, e - base);
        int c = 0; float ww = 0.f;
        if (lane < n) { int2 p = cw[rbase + base + lane]; c = p.x; ww = __int_as_float(p.y); }
        gchunk(c, ww, n, t2, f, ax, ay, bx, by);
    }
}

// Step 0: full-row gather; stores external-col part to predc (reused 7 steps).
__global__ __launch_bounds__(256) void k_pred_first(
    const int* __restrict__ nintA, const int* __restrict__ cnt,
    const int2* __restrict__ cw, const float2* __restrict__ vals2,
    float2* __restrict__ predc2, const bf2* __restrict__ th2,
    float2* __restrict__ err2, bf2* __restrict__ dd2, int N, int NI) {
    const int r = (int)blockIdx.x * 2 + ((int)threadIdx.x >> 7);
    if (r >= N) return;
    const int f = (int)threadIdx.x & 127;
    const int lane = (int)threadIdx.x & 63;
    const int rbase = r * CAP;
    const int2 p0 = cw[rbase + lane];          // speculative chunk 0
    const int ni = nintA[r];
    const int de = min(cnt[r], CAP);
    // internal-col part
    float ix = 0.f, iy = 0.f, jx = 0.f, jy = 0.f;
    gchunk(p0.x, __int_as_float(p0.y), min(64, ni), th2, f, ix, iy, jx, jy);
    gtail(cw, rbase, 64, ni, lane, th2, f, ix, iy, jx, jy);
    // external-col part
    float xx = 0.f, xy = 0.f, yx = 0.f, yy = 0.f;
    gtail(cw, rbase, ni, de, lane, th2, f, xx, xy, yx, yy);
    const int idx = r * F2 + f;
    const float pcx = xx + yx, pcy = xy + yy;
    predc2[idx] = make_float2(pcx, pcy);
    const float2 v = vals2[idx];
    const float ex = v.x - (pcx + ix + jx);
    const float ey = v.y - (pcy + iy + jy);
    if (r < NI) err2[idx] = make_float2(ex, ey);
    const float ux = ftanh(ex), uy = ftanh(ey);
    dd2[idx] = f22bf(1.f - ux * ux, 1.f - uy * uy);
}

// Steps 1..7: internal-col gather + cached predc.
__global__ __launch_bounds__(256) void k_pred(
    const int* __restrict__ nintA, const int2* __restrict__ cw,
    const float2* __restrict__ vals2, const float2* __restrict__ predc2,
    const bf2* __restrict__ th2, float2* __restrict__ err2,
    bf2* __restrict__ dd2, int N, int NI) {
    const int r = (int)blockIdx.x * 2 + ((int)threadIdx.x >> 7);
    if (r >= N) return;
    const int f = (int)threadIdx.x & 127;
    const int lane = (int)threadIdx.x & 63;
    const int rbase = r * CAP;
    const int2 p0 = cw[rbase + lane];          // speculative chunk 0
    const int ni = nintA[r];
    float ax = 0.f, ay = 0.f, bx = 0.f, by = 0.f;
    gchunk(p0.x, __int_as_float(p0.y), min(64, ni), th2, f, ax, ay, bx, by);
    gtail(cw, rbase, 64, ni, lane, th2, f, ax, ay, bx, by);
    const int idx = r * F2 + f;
    const float2 pc = predc2[idx];
    const float2 v  = vals2[idx];
    const float ex = v.x - (pc.x + ax + bx);
    const float ey = v.y - (pc.y + ay + by);
    if (r < NI) err2[idx] = make_float2(ex, ey);
    const float ux = ftanh(ex), uy = ftanh(ey);
    dd2[idx] = f22bf(1.f - ux * ux, 1.f - uy * uy);
}

// Internal rows: g = sum w_e*dd[col]; vals -= lr*(err-g); th = tanh(vals).
// writeTh=0 on the last step (th dead afterwards).
__global__ __launch_bounds__(256) void k_grad(
    const int* __restrict__ cnt, const int2* __restrict__ cw,
    const float2* __restrict__ err2, const bf2* __restrict__ dd2,
    float2* __restrict__ vals2, bf2* __restrict__ th2, int NI, int writeTh) {
    const int r = (int)blockIdx.x * 2 + ((int)threadIdx.x >> 7);
    if (r >= NI) return;
    const int f = (int)threadIdx.x & 127;
    const int lane = (int)threadIdx.x & 63;
    const int rbase = r * CAP;
    const int2 p0 = cw[rbase + lane];          // speculative chunk 0
    const int de = min(cnt[r], CAP);
    float ax = 0.f, ay = 0.f, bx = 0.f, by = 0.f;
    gchunk(p0.x, __int_as_float(p0.y), min(64, de), dd2, f, ax, ay, bx, by);
    gtail(cw, rbase, 64, de, lane, dd2, f, ax, ay, bx, by);
    const int idx = r * F2 + f;
    const float2 er = err2[idx];
    const float2 v  = vals2[idx];
    const float nx = v.x - LR_X * (er.x - (ax + bx));
    const float ny = v.y - LR_X * (er.y - (ay + by));
    vals2[idx] = make_float2(nx, ny);
    if (writeTh) th2[idx] = f22bf(ftanh(nx), ftanh(ny));
}

// ---- Launch ---------------------------------------------------------------

extern "C" void kernel_launch(void* const* d_in, const int* in_sizes, int n_in,
                              void* d_out, int out_size, void* d_ws, size_t ws_size,
                              hipStream_t stream) {
    const float* values = (const float*)d_in[0];
    const float* w      = (const float*)d_in[1];
    const int*   edge   = (const int*)d_in[2];
    const int NF = in_sizes[0];            // N*F
    const int N  = NF / FDIM;              // 5000
    const int E  = in_sizes[2] / 2;        // 160000
    const int NI = in_sizes[3];            // 2500
    const int NF2 = NF / 2;
    const int* srcp = edge;
    const int* dstp = edge + E;
    float* vals = (float*)d_out;

    char* ws = (char*)d_ws;
    size_t off = 0;
    auto alloc = [&](size_t bytes) {
        void* p = ws + off;
        off = (off + bytes + 255) & ~(size_t)255;
        return p;
    };
    int*  cnt   = (int*) alloc((size_t)N * sizeof(int));
    int*  nintA = (int*) alloc((size_t)N * sizeof(int));
    int*  keyT  = (int*) alloc((size_t)N * CAP * sizeof(int));
    int*  colS  = (int*) alloc((size_t)N * CAP * sizeof(int));
    int2* cw    = (int2*)alloc((size_t)N * CAP * sizeof(int2));
    bf2*  th2   = (bf2*) alloc((size_t)NF2 * sizeof(bf2));
    bf2*  dd2   = (bf2*) alloc((size_t)NF2 * sizeof(bf2));
    float* err   = (float*)alloc((size_t)NF * sizeof(float));
    float* predc = (float*)alloc((size_t)NF * sizeof(float));
    (void)ws_size; (void)n_in; (void)out_size;

    float2* vals2  = (float2*)vals;
    float2* err2   = (float2*)err;
    float2* predc2 = (float2*)predc;

    hipMemsetAsync(cnt, 0, (size_t)N * sizeof(int), stream);
    const int gE   = (E + 255) / 256;
    const int gNF2 = (NF2 + 255) / 256;
    k_fill_init<<<gE + gNF2, 256, 0, stream>>>(srcp, dstp, cnt, keyT, colS, E, NI,
                                               values, vals, th2, NF2, gE);
    k_rank_scatter<<<(N + 3) / 4, 256, 0, stream>>>(keyT, colS, cnt, w, cw, nintA, N, N);

    const int gP = (N + 1) / 2;
    const int gG = (NI + 1) / 2;
    for (int t = 0; t < T_STEPS; ++t) {
        if (t == 0)
            k_pred_first<<<gP, 256, 0, stream>>>(nintA, cnt, cw, vals2, predc2, th2, err2, dd2, N, NI);
        else
            k_pred<<<gP, 256, 0, stream>>>(nintA, cw, vals2, predc2, th2, err2, dd2, N, NI);
        k_grad<<<gG, 256, 0, stream>>>(cnt, cw, err2, dd2, vals2, th2, NI,
                                       (t == T_STEPS - 1) ? 0 : 1);
    }
}